// Round 1
// baseline (217.355 us; speedup 1.0000x reference)
//
#include <hip/hip_runtime.h>
#include <math.h>

#define BB 64
#define RR 2048
#define HH 1024
#define EE 512
#define DD 1024
#define RCH 16          // r-chunks in kernel 4
#define RPC (RR / RCH)  // 128 regions per chunk

__device__ __forceinline__ float fast_tanh(float x) {
    // tanh(x) = 1 - 2/(exp(2x)+1); exact limits at +/-inf, ~1e-7 rel err via v_exp/v_rcp
    float e = __expf(2.0f * x);
    return 1.0f - 2.0f * __builtin_amdgcn_rcpf(e + 1.0f);
}

// K1: wh[b][e] = sum_h hidden[b][h] * w_h[h][e]
__global__ __launch_bounds__(512) void k_wh(const float* __restrict__ hidden,
                                            const float* __restrict__ w_h,
                                            float* __restrict__ wh) {
    __shared__ float sh[HH];
    const int b = blockIdx.x;
    const int e = threadIdx.x;  // 0..511
    for (int h = threadIdx.x; h < HH; h += 512) sh[h] = hidden[b * HH + h];
    __syncthreads();
    float acc = 0.f;
#pragma unroll 8
    for (int h = 0; h < HH; ++h) acc = fmaf(sh[h], w_h[h * EE + e], acc);
    wh[b * EE + e] = acc;
}

// K2: logits[b][r] = sum_e tanh(wh[b][e] + p_att[b][r][e]) * w_alpha[e] + mask[b][r]
// One wave (64 lanes) per (b,r) row; lane covers 8 elements via two float4 loads.
__global__ __launch_bounds__(256) void k_logits(const float* __restrict__ p_att,
                                                const float* __restrict__ wh,
                                                const float* __restrict__ w_alpha,
                                                const float* __restrict__ mask,
                                                float* __restrict__ logits) {
    const int wave = threadIdx.x >> 6;
    const int lane = threadIdx.x & 63;
    const int row = blockIdx.x * 4 + wave;     // 0 .. B*R-1 (131072)
    const int b = row >> 11;                   // / RR
    const float* __restrict__ p = p_att + (long long)row * EE;
    const float* __restrict__ whb = wh + b * EE;
    float s = 0.f;
#pragma unroll
    for (int half = 0; half < 2; ++half) {
        const int e0 = half * 256 + lane * 4;
        float4 pv = *(const float4*)(p + e0);
        float4 wv = *(const float4*)(whb + e0);
        float4 av = *(const float4*)(w_alpha + e0);
        s = fmaf(fast_tanh(pv.x + wv.x), av.x, s);
        s = fmaf(fast_tanh(pv.y + wv.y), av.y, s);
        s = fmaf(fast_tanh(pv.z + wv.z), av.z, s);
        s = fmaf(fast_tanh(pv.w + wv.w), av.w, s);
    }
#pragma unroll
    for (int off = 32; off; off >>= 1) s += __shfl_xor(s, off);
    if (lane == 0) logits[row] = s + mask[row];
}

// K3: alpha[b][:] = softmax(logits[b][:]) over R=2048, one block per b
__global__ __launch_bounds__(256) void k_softmax(const float* __restrict__ logits,
                                                 float* __restrict__ alpha) {
    const int b = blockIdx.x;
    const int t = threadIdx.x;
    const int wave = t >> 6, lane = t & 63;
    __shared__ float smax[4], ssum[4];
    float v[8];
    float m = -INFINITY;
#pragma unroll
    for (int i = 0; i < 8; ++i) {
        v[i] = logits[b * RR + i * 256 + t];
        m = fmaxf(m, v[i]);
    }
#pragma unroll
    for (int off = 32; off; off >>= 1) m = fmaxf(m, __shfl_xor(m, off));
    if (lane == 0) smax[wave] = m;
    __syncthreads();
    m = fmaxf(fmaxf(smax[0], smax[1]), fmaxf(smax[2], smax[3]));
    float s = 0.f;
#pragma unroll
    for (int i = 0; i < 8; ++i) {
        v[i] = __expf(v[i] - m);
        s += v[i];
    }
#pragma unroll
    for (int off = 32; off; off >>= 1) s += __shfl_xor(s, off);
    if (lane == 0) ssum[wave] = s;
    __syncthreads();
    s = ssum[0] + ssum[1] + ssum[2] + ssum[3];
    const float inv = 1.0f / s;
#pragma unroll
    for (int i = 0; i < 8; ++i) alpha[b * RR + i * 256 + t] = v[i] * inv;
}

// K4: part[b][rc][d] = sum_{r in chunk rc} alpha[b][r] * feats[b][r][d]
// block: 256 threads, each owns a float4 of d (covers all D=1024)
__global__ __launch_bounds__(256) void k_att_partial(const float* __restrict__ alpha,
                                                     const float* __restrict__ feats,
                                                     float* __restrict__ part) {
    const int b = blockIdx.x;
    const int rc = blockIdx.y;
    const int t = threadIdx.x;
    __shared__ float sa[RPC];
    if (t < RPC) sa[t] = alpha[b * RR + rc * RPC + t];
    __syncthreads();
    const float* __restrict__ fp =
        feats + ((long long)b * RR + (long long)rc * RPC) * DD + t * 4;
    float4 acc = {0.f, 0.f, 0.f, 0.f};
#pragma unroll 8
    for (int r = 0; r < RPC; ++r) {
        const float a = sa[r];
        float4 f = *(const float4*)(fp + (long long)r * DD);
        acc.x = fmaf(a, f.x, acc.x);
        acc.y = fmaf(a, f.y, acc.y);
        acc.z = fmaf(a, f.z, acc.z);
        acc.w = fmaf(a, f.w, acc.w);
    }
    *((float4*)(part + (long long)(b * RCH + rc) * DD) + t) = acc;
}

// K5: out[b][d] = sum_rc part[b][rc][d]   (deterministic 16-way reduce)
__global__ __launch_bounds__(256) void k_att_reduce(const float* __restrict__ part,
                                                    float* __restrict__ out) {
    const int idx = blockIdx.x * 256 + threadIdx.x;  // b*D + d, 65536 total
    const int b = idx >> 10;
    const int d = idx & 1023;
    float s = 0.f;
#pragma unroll
    for (int rc = 0; rc < RCH; ++rc) s += part[(long long)(b * RCH + rc) * DD + d];
    out[idx] = s;
}

extern "C" void kernel_launch(void* const* d_in, const int* in_sizes, int n_in,
                              void* d_out, int out_size, void* d_ws, size_t ws_size,
                              hipStream_t stream) {
    const float* hidden  = (const float*)d_in[0];  // [B,H]
    const float* feats   = (const float*)d_in[1];  // [B,R,D]
    const float* p_att   = (const float*)d_in[2];  // [B,R,E]
    const float* mask    = (const float*)d_in[3];  // [B,R]
    const float* w_h     = (const float*)d_in[4];  // [H,E]
    const float* w_alpha = (const float*)d_in[5];  // [E]
    float* out = (float*)d_out;                    // [B,D]

    char* ws = (char*)d_ws;
    float* wh     = (float*)(ws);                         // 64*512*4   = 128 KB
    float* logits = (float*)(ws + (size_t)131072);        // 64*2048*4  = 512 KB
    float* alpha  = (float*)(ws + (size_t)655360);        // 64*2048*4  = 512 KB
    float* part   = (float*)(ws + (size_t)1179648);       // 64*16*1024*4 = 4 MB

    k_wh<<<BB, 512, 0, stream>>>(hidden, w_h, wh);
    k_logits<<<(BB * RR) / 4, 256, 0, stream>>>(p_att, wh, w_alpha, mask, logits);
    k_softmax<<<BB, 256, 0, stream>>>(logits, alpha);
    k_att_partial<<<dim3(BB, RCH), 256, 0, stream>>>(alpha, feats, part);
    k_att_reduce<<<(BB * DD) / 256, 256, 0, stream>>>(part, out);
}

// Round 2
// 191.315 us; speedup vs baseline: 1.1361x; 1.1361x over previous
//
#include <hip/hip_runtime.h>
#include <math.h>

#define BB 64
#define RR 2048
#define HH 1024
#define EE 512
#define DD 1024
#define RCH 32          // r-chunks in kernel 4
#define RPC (RR / RCH)  // 64 regions per chunk
#define NRW 4           // rows per wave in kernel 2

typedef float f32x4 __attribute__((ext_vector_type(4)));

__device__ __forceinline__ float fast_tanh(float x) {
    // tanh(x) = 1 - 2/(exp(2x)+1); exact limits at +/-inf
    float e = __expf(2.0f * x);
    return 1.0f - 2.0f * __builtin_amdgcn_rcpf(e + 1.0f);
}

// K1: wh[b][e] = sum_h hidden[b][h] * w_h[h][e]; grid (B, 4), block 128
__global__ __launch_bounds__(128) void k_wh(const float* __restrict__ hidden,
                                            const float* __restrict__ w_h,
                                            float* __restrict__ wh) {
    __shared__ float sh[HH];
    const int b = blockIdx.x;
    const int e = blockIdx.y * 128 + threadIdx.x;
    for (int h = threadIdx.x; h < HH; h += 128) sh[h] = hidden[b * HH + h];
    __syncthreads();
    float acc = 0.f;
#pragma unroll 8
    for (int h = 0; h < HH; ++h) acc = fmaf(sh[h], w_h[h * EE + e], acc);
    wh[b * EE + e] = acc;
}

// K2: logits[b][r] = sum_e tanh(wh[b][e] + p_att[b][r][e]) * w_alpha[e] + mask[b][r]
// One wave per NRW consecutive rows; wh & w_alpha cached in registers.
__global__ __launch_bounds__(256) void k_logits(const float* __restrict__ p_att,
                                                const float* __restrict__ wh,
                                                const float* __restrict__ w_alpha,
                                                const float* __restrict__ mask,
                                                float* __restrict__ logits) {
    const int wave = threadIdx.x >> 6;
    const int lane = threadIdx.x & 63;
    const long long row0 = ((long long)blockIdx.x * 4 + wave) * NRW;
    const int b = (int)(row0 >> 11);  // / RR; NRW rows never cross a b boundary
    const float* __restrict__ whb = wh + b * EE;
    const f32x4 wh0 = *(const f32x4*)(whb + lane * 4);
    const f32x4 wh1 = *(const f32x4*)(whb + 256 + lane * 4);
    const f32x4 wa0 = *(const f32x4*)(w_alpha + lane * 4);
    const f32x4 wa1 = *(const f32x4*)(w_alpha + 256 + lane * 4);
    const f32x4* __restrict__ pbase = (const f32x4*)(p_att + row0 * EE);
#pragma unroll
    for (int r = 0; r < NRW; ++r) {
        const f32x4* __restrict__ pr = pbase + (long long)r * (EE / 4);
        f32x4 p0 = __builtin_nontemporal_load(pr + lane);
        f32x4 p1 = __builtin_nontemporal_load(pr + 64 + lane);
        float s;
        s = fast_tanh(p0.x + wh0.x) * wa0.x;
        s = fmaf(fast_tanh(p0.y + wh0.y), wa0.y, s);
        s = fmaf(fast_tanh(p0.z + wh0.z), wa0.z, s);
        s = fmaf(fast_tanh(p0.w + wh0.w), wa0.w, s);
        s = fmaf(fast_tanh(p1.x + wh1.x), wa1.x, s);
        s = fmaf(fast_tanh(p1.y + wh1.y), wa1.y, s);
        s = fmaf(fast_tanh(p1.z + wh1.z), wa1.z, s);
        s = fmaf(fast_tanh(p1.w + wh1.w), wa1.w, s);
#pragma unroll
        for (int off = 32; off; off >>= 1) s += __shfl_xor(s, off);
        if (lane == 0) {
            const long long row = row0 + r;
            logits[row] = s + mask[row];
        }
    }
}

// K3: alpha[b][:] = softmax(logits[b][:]) over R=2048, one block per b
__global__ __launch_bounds__(256) void k_softmax(const float* __restrict__ logits,
                                                 float* __restrict__ alpha) {
    const int b = blockIdx.x;
    const int t = threadIdx.x;
    const int wave = t >> 6, lane = t & 63;
    __shared__ float smax[4], ssum[4];
    float v[8];
    float m = -INFINITY;
#pragma unroll
    for (int i = 0; i < 8; ++i) {
        v[i] = logits[b * RR + i * 256 + t];
        m = fmaxf(m, v[i]);
    }
#pragma unroll
    for (int off = 32; off; off >>= 1) m = fmaxf(m, __shfl_xor(m, off));
    if (lane == 0) smax[wave] = m;
    __syncthreads();
    m = fmaxf(fmaxf(smax[0], smax[1]), fmaxf(smax[2], smax[3]));
    float s = 0.f;
#pragma unroll
    for (int i = 0; i < 8; ++i) {
        v[i] = __expf(v[i] - m);
        s += v[i];
    }
#pragma unroll
    for (int off = 32; off; off >>= 1) s += __shfl_xor(s, off);
    if (lane == 0) ssum[wave] = s;
    __syncthreads();
    s = ssum[0] + ssum[1] + ssum[2] + ssum[3];
    const float inv = 1.0f / s;
#pragma unroll
    for (int i = 0; i < 8; ++i) alpha[b * RR + i * 256 + t] = v[i] * inv;
}

// K4: part[b][rc][d] = sum_{r in chunk rc} alpha[b][r] * feats[b][r][d]
// grid (B, RCH), block 256; thread owns one float4 of d.
__global__ __launch_bounds__(256) void k_att_partial(const float* __restrict__ alpha,
                                                     const float* __restrict__ feats,
                                                     float* __restrict__ part) {
    const int b = blockIdx.x;
    const int rc = blockIdx.y;
    const int t = threadIdx.x;
    __shared__ float sa[RPC];
    if (t < RPC) sa[t] = alpha[b * RR + rc * RPC + t];
    __syncthreads();
    const f32x4* __restrict__ fp =
        (const f32x4*)(feats + ((long long)b * RR + (long long)rc * RPC) * DD) + t;
    f32x4 acc = {0.f, 0.f, 0.f, 0.f};
#pragma unroll 8
    for (int r = 0; r < RPC; ++r) {
        const float a = sa[r];
        f32x4 f = __builtin_nontemporal_load(fp + r * (DD / 4));
        acc.x = fmaf(a, f.x, acc.x);
        acc.y = fmaf(a, f.y, acc.y);
        acc.z = fmaf(a, f.z, acc.z);
        acc.w = fmaf(a, f.w, acc.w);
    }
    *((f32x4*)(part + (long long)(b * RCH + rc) * DD) + t) = acc;
}

// K5: out[b][d] = sum_rc part[b][rc][d]   (deterministic RCH-way reduce)
__global__ __launch_bounds__(256) void k_att_reduce(const float* __restrict__ part,
                                                    float* __restrict__ out) {
    const int idx = blockIdx.x * 256 + threadIdx.x;  // b*D + d, 65536 total
    const int b = idx >> 10;
    const int d = idx & 1023;
    float s = 0.f;
#pragma unroll
    for (int rc = 0; rc < RCH; ++rc) s += part[(long long)(b * RCH + rc) * DD + d];
    out[idx] = s;
}

extern "C" void kernel_launch(void* const* d_in, const int* in_sizes, int n_in,
                              void* d_out, int out_size, void* d_ws, size_t ws_size,
                              hipStream_t stream) {
    const float* hidden  = (const float*)d_in[0];  // [B,H]
    const float* feats   = (const float*)d_in[1];  // [B,R,D]
    const float* p_att   = (const float*)d_in[2];  // [B,R,E]
    const float* mask    = (const float*)d_in[3];  // [B,R]
    const float* w_h     = (const float*)d_in[4];  // [H,E]
    const float* w_alpha = (const float*)d_in[5];  // [E]
    float* out = (float*)d_out;                    // [B,D]

    char* ws = (char*)d_ws;
    float* wh     = (float*)(ws);                   // 64*512*4   = 128 KB
    float* logits = (float*)(ws + (size_t)131072);  // 64*2048*4  = 512 KB
    float* alpha  = (float*)(ws + (size_t)655360);  // 64*2048*4  = 512 KB
    float* part   = (float*)(ws + (size_t)1179648); // 64*32*1024*4 = 8 MB

    k_wh<<<dim3(BB, 4), 128, 0, stream>>>(hidden, w_h, wh);
    k_logits<<<(BB * RR) / (4 * NRW), 256, 0, stream>>>(p_att, wh, w_alpha, mask, logits);
    k_softmax<<<BB, 256, 0, stream>>>(logits, alpha);
    k_att_partial<<<dim3(BB, RCH), 256, 0, stream>>>(alpha, feats, part);
    k_att_reduce<<<(BB * DD) / 256, 256, 0, stream>>>(part, out);
}

// Round 3
// 162.145 us; speedup vs baseline: 1.3405x; 1.1799x over previous
//
#include <hip/hip_runtime.h>
#include <math.h>

#define BB 64
#define RR 2048
#define HH 1024
#define EE 512
#define DD 1024
#define RC 32           // r-chunks (blocks per b) in fused kernel
#define RPB (RR / RC)   // 64 rows per block
#define RPW (RPB / 4)   // 16 rows per wave

typedef float f32x4 __attribute__((ext_vector_type(4)));

__device__ __forceinline__ float fast_tanh(float x) {
    // tanh(x) = 1 - 2/(exp(2x)+1); exact limits at +/-inf
    float e = __expf(2.0f * x);
    return 1.0f - 2.0f * __builtin_amdgcn_rcpf(e + 1.0f);
}

// K1: wh[b][e] = sum_h hidden[b][h] * w_h[h][e]
// grid (B, E/64), block 256 = 4 waves; wave owns an h-segment, LDS-reduce.
__global__ __launch_bounds__(256) void k_wh(const float* __restrict__ hidden,
                                            const float* __restrict__ w_h,
                                            float* __restrict__ wh) {
    __shared__ float sh[HH];
    __shared__ float sred[4][64];
    const int b = blockIdx.x;
    const int t = threadIdx.x;
    const int lane = t & 63, hseg = t >> 6;
    const int e = blockIdx.y * 64 + lane;
    for (int h = t; h < HH; h += 256) sh[h] = hidden[b * HH + h];
    __syncthreads();
    const int h0 = hseg * 256;
    float acc = 0.f;
#pragma unroll 8
    for (int h = 0; h < 256; ++h) acc = fmaf(sh[h0 + h], w_h[(h0 + h) * EE + e], acc);
    sred[hseg][lane] = acc;
    __syncthreads();
    if (t < 64)
        wh[b * EE + blockIdx.y * 64 + t] =
            (sred[0][t] + sred[1][t]) + (sred[2][t] + sred[3][t]);
}

// Fused K2+K3+K4: per (b, rc) block of 64 rows:
//   phase 1: w[r] = exp(logit[r] + mask[r])   (no max subtraction -- logits bounded)
//   phase 2: num[d] = sum_r w[r] * feats[r][d];  den = sum_r w[r]
__global__ __launch_bounds__(256) void k_fused(const float* __restrict__ p_att,
                                               const float* __restrict__ feats,
                                               const float* __restrict__ wh,
                                               const float* __restrict__ w_alpha,
                                               const float* __restrict__ mask,
                                               float* __restrict__ num,
                                               float* __restrict__ den) {
    __shared__ float sw[RPB];
    const int b = blockIdx.x, rc = blockIdx.y;
    const int t = threadIdx.x, wave = t >> 6, lane = t & 63;
    const int r0 = rc * RPB;

    // ---- phase 1: logits for this chunk (16 rows per wave) ----
    const float* __restrict__ whb = wh + b * EE;
    const f32x4 wh0 = *(const f32x4*)(whb + lane * 4);
    const f32x4 wh1 = *(const f32x4*)(whb + 256 + lane * 4);
    const f32x4 wa0 = *(const f32x4*)(w_alpha + lane * 4);
    const f32x4 wa1 = *(const f32x4*)(w_alpha + 256 + lane * 4);
    const long long rowb = (long long)b * RR + r0 + wave * RPW;
    const f32x4* __restrict__ pb = (const f32x4*)(p_att + rowb * EE);
#pragma unroll 4
    for (int rr = 0; rr < RPW; ++rr) {
        f32x4 p0 = __builtin_nontemporal_load(pb + rr * (EE / 4) + lane);
        f32x4 p1 = __builtin_nontemporal_load(pb + rr * (EE / 4) + 64 + lane);
        float s;
        s = fast_tanh(p0.x + wh0.x) * wa0.x;
        s = fmaf(fast_tanh(p0.y + wh0.y), wa0.y, s);
        s = fmaf(fast_tanh(p0.z + wh0.z), wa0.z, s);
        s = fmaf(fast_tanh(p0.w + wh0.w), wa0.w, s);
        s = fmaf(fast_tanh(p1.x + wh1.x), wa1.x, s);
        s = fmaf(fast_tanh(p1.y + wh1.y), wa1.y, s);
        s = fmaf(fast_tanh(p1.z + wh1.z), wa1.z, s);
        s = fmaf(fast_tanh(p1.w + wh1.w), wa1.w, s);
#pragma unroll
        for (int off = 32; off; off >>= 1) s += __shfl_xor(s, off);
        if (lane == 0) sw[wave * RPW + rr] = __expf(s + mask[rowb + rr]);
    }
    __syncthreads();

    // ---- phase 2: weighted partial sum over feats; thread owns float4 of d ----
    const f32x4* __restrict__ fb =
        (const f32x4*)(feats + ((long long)b * RR + r0) * DD) + t;
    f32x4 acc = {0.f, 0.f, 0.f, 0.f};
#pragma unroll 8
    for (int r = 0; r < RPB; ++r) {
        const float a = sw[r];
        f32x4 f = __builtin_nontemporal_load(fb + r * (DD / 4));
        acc.x = fmaf(a, f.x, acc.x);
        acc.y = fmaf(a, f.y, acc.y);
        acc.z = fmaf(a, f.z, acc.z);
        acc.w = fmaf(a, f.w, acc.w);
    }
    ((f32x4*)(num + (long long)(b * RC + rc) * DD))[t] = acc;
    if (t == 0) {
        float d = 0.f;
#pragma unroll
        for (int r = 0; r < RPB; ++r) d += sw[r];
        den[b * RC + rc] = d;
    }
}

// K3: out[b][d] = sum_rc num[b][rc][d] / sum_rc den[b][rc]
__global__ __launch_bounds__(256) void k_out(const float* __restrict__ num,
                                             const float* __restrict__ den,
                                             float* __restrict__ out) {
    const int idx = blockIdx.x * 256 + threadIdx.x;  // b*D + d
    const int b = idx >> 10;
    const int d = idx & 1023;
    float ds = 0.f;
#pragma unroll
    for (int rc = 0; rc < RC; ++rc) ds += den[b * RC + rc];
    float ns = 0.f;
#pragma unroll
    for (int rc = 0; rc < RC; ++rc)
        ns += num[((long long)(b * RC + rc) << 10) + d];
    out[idx] = ns / ds;
}

extern "C" void kernel_launch(void* const* d_in, const int* in_sizes, int n_in,
                              void* d_out, int out_size, void* d_ws, size_t ws_size,
                              hipStream_t stream) {
    const float* hidden  = (const float*)d_in[0];  // [B,H]
    const float* feats   = (const float*)d_in[1];  // [B,R,D]
    const float* p_att   = (const float*)d_in[2];  // [B,R,E]
    const float* mask    = (const float*)d_in[3];  // [B,R]
    const float* w_h     = (const float*)d_in[4];  // [H,E]
    const float* w_alpha = (const float*)d_in[5];  // [E]
    float* out = (float*)d_out;                    // [B,D]

    char* ws = (char*)d_ws;
    float* wh  = (float*)(ws);                       // 64*512*4 = 128 KB
    float* num = (float*)(ws + (size_t)131072);      // 64*32*1024*4 = 8 MB
    float* den = (float*)(ws + (size_t)(131072 + 8388608));  // 64*32*4 = 8 KB

    k_wh<<<dim3(BB, EE / 64), 256, 0, stream>>>(hidden, w_h, wh);
    k_fused<<<dim3(BB, RC), 256, 0, stream>>>(p_att, feats, wh, w_alpha, mask, num, den);
    k_out<<<(BB * DD) / 256, 256, 0, stream>>>(num, den, out);
}